// Round 15
// baseline (3740.538 us; speedup 1.0000x reference)
//
#include <hip/hip_runtime.h>

static constexpr int B_ = 8;
static constexpr int C_ = 64;
static constexpr int H_ = 256;
static constexpr int W_ = 512;
static constexpr int K_ = 9;
static constexpr int PAD_ = 4;

static constexpr int T_ = 16;     // own cols per block (MFMA N)
static constexpr int WC_ = 36;    // prevT window cols: 4 pad + 8 L + 16 own + 8 R
static constexpr int CIW_ = 72;   // LDS ci-row width (64 + 8 pad; 2-way b128 only)
static constexpr int NB_ = 8;     // chain-neighbor stride in blockIdx

typedef unsigned long long u64;
typedef unsigned int u32;
typedef __attribute__((ext_vector_type(8))) short bf16x8;
typedef __attribute__((ext_vector_type(4))) float f32x4;

// workspace layout (bytes). Halo/tags SHARED across the 4 sequential
// directions (tag values are dir-offset, monotonically increasing).
static constexpr size_t XCC_OFF = 0;                 // 4 dirs x 256 x 4 B
static constexpr size_t TAG_OFF = 64ull << 10;       // 1024 slots x 64 B
static constexpr size_t INIT_BYTES = 128ull << 10;   // zero XCC + tags
static constexpr size_t HALO_OFF = 1ull << 20;       // 1024 slots x 192 u64
static constexpr size_t SLOT_U64 = 192;              // r 128 + x 64
static constexpr size_t TBUF_OFF = 4ull << 20;       // transpose buffer

// ---------- sync primitives (r13/r14-proven; r9/r10/r12 failure ledger:
// cross-block traffic must be atomic RMWs end-to-end) ----------
__device__ __forceinline__ void l2_put_u64(u64* p, u64 v) {
    asm volatile("global_atomic_swap_x2 %0, %1, off" :: "v"(p), "v"(v)
                 : "memory");
}
__device__ __forceinline__ u64 l2_get_u64(const u64* p) {
    u64 v;
    asm volatile("global_atomic_add_x2 %0, %1, %2, off sc0\n\t"
                 "s_waitcnt vmcnt(0)"
                 : "=&v"(v) : "v"(p), "v"(0ull) : "memory");
    return v;
}
__device__ __forceinline__ u64 ic_get_u64(const u64* p) {
    return __hip_atomic_load(p, __ATOMIC_RELAXED, __HIP_MEMORY_SCOPE_AGENT);
}
__device__ __forceinline__ void ic_put_u64(u64* p, u64 v) {
    (void)__hip_atomic_exchange(p, v, __ATOMIC_RELAXED,
                                __HIP_MEMORY_SCOPE_AGENT);
}
__device__ __forceinline__ u64 halo_put(u64* p, u64 v, bool ic) {
    if (ic) ic_put_u64(p, v); else l2_put_u64(p, v);
    return 0;
}
__device__ __forceinline__ u64 halo_get(const u64* p, bool ic) {
    return ic ? ic_get_u64(p) : l2_get_u64(p);
}
__device__ __forceinline__ unsigned xcc_id() {
    unsigned v;
    asm volatile("s_getreg_b32 %0, hwreg(HW_REG_XCC_ID)" : "=s"(v));
    return v & 0xffu;
}
__device__ __forceinline__ unsigned short f2bf(float f) {
    const u32 u = __float_as_uint(f);
    return (unsigned short)((u + 0x7fffu + ((u >> 16) & 1u)) >> 16);
}
__device__ __forceinline__ float bf2f(unsigned short h) {
    return __uint_as_float((u32)h << 16);
}
__device__ __forceinline__ u64 pack4bf(const float* r) {
    return (u64)f2bf(r[0]) | ((u64)f2bf(r[1]) << 16) |
           ((u64)f2bf(r[2]) << 32) | ((u64)f2bf(r[3]) << 48);
}

// Persistent scan, MFMA conv, TRAPEZOID DEPTH 2: one halo exchange per 2
// rows. prevT window [t0-12, t0+24): col rel 0-3 = pad (garbage-read only),
// 4-11 = L refill, 12-27 = own, 28-35 = R refill. Substep 0 computes row r0
// over 2 MFMA tiles (valid [t0-4,t0+20): halo redundant compute uses
// imported bf16 x); substep 1 computes row r0+1 (own tile valid). Exchange:
// r = last row's own cols (8/side, 4-bf16/u64) + x = next first row's own
// edge cols (4/side) — ALL through the proven atomic channel (owner-only
// reads of x, no plain-load coherence anywhere). Central tags after the
// vmcnt-draining __syncthreads; l2/IC flavor per runtime XCC check;
// parity-2 slots; tag = tagBase + g + 1, monotone across shared dirs.
__global__ __launch_bounds__(256, 1) void scan_trap_kernel(
    float* __restrict__ buf, const float* __restrict__ w,
    const float* __restrict__ bias, const int N,
    const long long rowStride, const long long colStride,
    const long long chanStride, const int startRow, const int rowDir,
    const int numSteps, u64* __restrict__ halo, u64* __restrict__ tags,
    unsigned* __restrict__ xccmap, const u64 tagBase)
{
    __shared__ __attribute__((aligned(16))) unsigned short prevT[WC_][CIW_];
    __shared__ __attribute__((aligned(8))) unsigned short xh[2][4][64];
    __shared__ unsigned s_ic[2];

    const int tid = threadIdx.x;
    const int wv = tid >> 6;
    const int lane = tid & 63;
    const int n = lane & 15;
    const int q = lane >> 4;
    const int coq = wv * 4 + q;
    const int co0 = coq * 4;
    const int blk = blockIdx.x;
    const int b = blk & 7;
    const int tile = blk >> 3;
    const int TPB = N / T_;
    const int t0 = tile * T_;
    const bool hasL = tile > 0;
    const bool hasR = tile < TPB - 1;
    // own col: tile0-own (n>=8) -> t0+n-8 ; tile1-own (n<8) -> t0+8+n
    const int ownc = (n >= 8) ? (t0 + n - 8) : (t0 + 8 + n);

    // ---- one-time link-scope discovery (r13 verbatim) ----
    bool icL = hasL, icR = hasR;
    if (halo != nullptr) {
        if (tid == 0) {
            const unsigned my = xcc_id();
            __hip_atomic_store(xccmap + blk, 0x100u | my, __ATOMIC_RELAXED,
                               __HIP_MEMORY_SCOPE_AGENT);
            unsigned xl = 0, xr = 0;
            if (hasL)
                while (!((xl = __hip_atomic_load(xccmap + blk - NB_,
                                                 __ATOMIC_RELAXED,
                                                 __HIP_MEMORY_SCOPE_AGENT)) &
                         0x100u))
                    __builtin_amdgcn_s_sleep(1);
            if (hasR)
                while (!((xr = __hip_atomic_load(xccmap + blk + NB_,
                                                 __ATOMIC_RELAXED,
                                                 __HIP_MEMORY_SCOPE_AGENT)) &
                         0x100u))
                    __builtin_amdgcn_s_sleep(1);
            s_ic[0] = (hasL && ((xl & 0xffu) != my)) ? 1u : 0u;
            s_ic[1] = (hasR && ((xr & 0xffu) != my)) ? 1u : 0u;
        }
        __syncthreads();
        icL = s_ic[0] != 0;
        icR = s_ic[1] != 0;
    }

    const long long base = (long long)b * C_ * chanStride;

    // ---- one-time: A-fragments (weights bf16) -> 18 x short8 (r14-proven)
    bf16x8 af[18];
    {
        const float* wr = w + (long long)(wv * 16 + n) * (C_ * K_);
#pragma unroll
        for (int t = 0; t < 18; ++t) {
            const int tap = t >> 1;
            const int ci0 = (t & 1) * 32 + q * 8;
            bf16x8 a;
#pragma unroll
            for (int j = 0; j < 8; ++j)
                a[j] = (short)f2bf(wr[(ci0 + j) * K_ + tap]);
            af[t] = a;
        }
    }
    float bv[4];
#pragma unroll
    for (int i = 0; i < 4; ++i) bv[i] = bias[co0 + i];

    // ---- initial staging: carry row (never written this dir) full window
    {
        const long long pr = base + (long long)(startRow - rowDir) * rowStride;
        for (int idx = tid; idx < WC_ * C_; idx += 256) {
            const int c = idx >> 6, ci = idx & 63;
            const int gc = t0 - 12 + c;
            float v = 0.f;
            if (gc >= 0 && gc < N)
                v = buf[pr + (long long)ci * chanStride +
                        (long long)gc * colStride];
            prevT[c][ci] = f2bf(v);
        }
        if (tid < 512) ((unsigned short*)xh)[tid] = 0;
    }

    float prevR[4] = {0.f, 0.f, 0.f, 0.f};  // own-col r of last computed row

    for (int s0 = 0; s0 < numSteps; s0 += 2) {
        const int g = s0 >> 1;
        const int d = (numSteps - s0 >= 2) ? 2 : 1;
        const int par = g & 1;

        // ================= EXCHANGE g =================
        if (halo != nullptr) {
            const u64 tagv = tagBase + (u64)g + 1;
            // export r (last row's own cols; skip at g=0 — staging covers)
            if (g > 0) {
                const int side = (n >= 8) ? 0 : 1;   // leftmost->0, right->1
                const bool has = side ? hasR : hasL;
                if (has) {
                    const bool ic = side ? icR : icL;
                    const int c = (n >= 8) ? (n - 8) : n;
                    u64* p = halo +
                        (size_t)((blk * 2 + par) * 2 + side) * SLOT_U64 +
                        c * 16 + coq;
                    halo_put(p, pack4bf(prevR), ic);
                }
            }
            // export x (next first row r0's own edge cols; owner-only reads)
            if (d == 2 && tid < 128) {
                const int side = tid >> 6, c = (tid >> 4) & 3, cq = tid & 15;
                const bool has = side ? hasR : hasL;
                if (has) {
                    const bool ic = side ? icR : icL;
                    const int col = t0 + (side ? 12 + c : c);
                    const long long orow =
                        base + (long long)(startRow + s0 * rowDir) * rowStride;
                    float f[4];
#pragma unroll
                    for (int i = 0; i < 4; ++i)
                        f[i] = buf[orow + (long long)(cq * 4 + i) * chanStride +
                                   (long long)col * colStride];
                    u64* p = halo +
                        (size_t)((blk * 2 + par) * 2 + side) * SLOT_U64 +
                        128 + c * 16 + cq;
                    halo_put(p, pack4bf(f), ic);
                }
            }
            __syncthreads();  // drain: all export atomics at L2/IC
            // publish tags FIRST (deadlock-safe), then poll
            if (tid == 0 && hasL)
                halo_put(tags + (size_t)((blk * 2 + par) * 2 + 0) * 8, tagv,
                         icL);
            if (tid == 64 && hasR)
                halo_put(tags + (size_t)((blk * 2 + par) * 2 + 1) * 8, tagv,
                         icR);
            if (tid == 0 && hasL) {
                const u64* tp =
                    tags + (size_t)(((blk - NB_) * 2 + par) * 2 + 1) * 8;
                while (halo_get(tp, icL) < tagv) __builtin_amdgcn_s_sleep(1);
            }
            if (tid == 64 && hasR) {
                const u64* tp =
                    tags + (size_t)(((blk + NB_) * 2 + par) * 2 + 0) * 8;
                while (halo_get(tp, icR) < tagv) __builtin_amdgcn_s_sleep(1);
            }
            __syncthreads();  // tags confirmed for all
            // import r -> side thirds of prevT (overwrites garbage regions)
            if (g > 0) {
                const int side = tid >> 7;           // 0=L, 1=R
                const int word = tid & 127, c = word >> 4, cq = word & 15;
                const bool has = side ? hasR : hasL;
                if (has) {
                    const bool ic = side ? icR : icL;
                    const int nb = side ? (blk + NB_) : (blk - NB_);
                    const u64* p = halo +
                        (size_t)((nb * 2 + par) * 2 + (side ^ 1)) * SLOT_U64 +
                        word;
                    const u64 v = halo_get(p, ic);
                    const int rel = side ? (28 + c) : (4 + c);
                    *(u64*)&prevT[rel][cq * 4] = v;
                }
            }
            // import x -> xh
            if (d == 2 && tid < 128) {
                const int side = tid >> 6, c = (tid >> 4) & 3, cq = tid & 15;
                const bool has = side ? hasR : hasL;
                if (has) {
                    const bool ic = side ? icR : icL;
                    const int nb = side ? (blk + NB_) : (blk - NB_);
                    const u64* p = halo +
                        (size_t)((nb * 2 + par) * 2 + (side ^ 1)) * SLOT_U64 +
                        128 + c * 16 + cq;
                    *(u64*)&xh[side][c][cq * 4] = halo_get(p, ic);
                }
            }
        }
        __syncthreads();  // SYNC_A

        // ================= SUBSTEPS =================
        for (int j = 0; j < d; ++j) {
            const int row = startRow + (s0 + j) * rowDir;
            const long long orow = base + (long long)row * rowStride;

            float xo[4];
#pragma unroll
            for (int i = 0; i < 4; ++i)
                xo[i] = buf[orow + (long long)(co0 + i) * chanStride +
                            (long long)ownc * colStride];

            f32x4 a0 = {0.f, 0.f, 0.f, 0.f};
            f32x4 a1 = {0.f, 0.f, 0.f, 0.f};
#pragma unroll
            for (int t = 0; t < 18; ++t) {
                const int tap = t >> 1;
                const int ci0 = (t & 1) * 32 + q * 8;
                const bf16x8 b0 = *(const bf16x8*)&prevT[n + tap][ci0];
                const bf16x8 b1 = *(const bf16x8*)&prevT[16 + n + tap][ci0];
                a0 = __builtin_amdgcn_mfma_f32_16x16x32_bf16(af[t], b0, a0,
                                                             0, 0, 0);
                a1 = __builtin_amdgcn_mfma_f32_16x16x32_bf16(af[t], b1, a1,
                                                             0, 0, 0);
            }

            // x sources: own col fp32; halo cols from imported bf16 x
            float xt0[4], xt1[4];
            {
                const u64 hvL = *(const u64*)&xh[0][(n - 4) & 3][co0];
                const u64 hvR = *(const u64*)&xh[1][(n - 8) & 3][co0];
#pragma unroll
                for (int i = 0; i < 4; ++i) {
                    xt0[i] = (n >= 8)
                                 ? xo[i]
                                 : bf2f((unsigned short)(hvL >> (16 * i)));
                    xt1[i] = (n < 8)
                                 ? xo[i]
                                 : bf2f((unsigned short)(hvR >> (16 * i)));
                }
            }
            float r0v[4], r1v[4];
#pragma unroll
            for (int i = 0; i < 4; ++i) {
                r0v[i] = xt0[i] + fmaxf(a0[i] + bv[i], 0.f);
                r1v[i] = xt1[i] + fmaxf(a1[i] + bv[i], 0.f);
            }
#pragma unroll
            for (int i = 0; i < 4; ++i)
                prevR[i] = (n >= 8) ? r0v[i] : r1v[i];

            __syncthreads();  // all prevT reads done

            // write-back row into prevT (image-bounds guard keeps OOI zeros)
            const int g0 = t0 - 8 + n;
            if (g0 >= 0) *(u64*)&prevT[4 + n][co0] = pack4bf(r0v);
            const int g1 = t0 + 8 + n;
            if (g1 < N) *(u64*)&prevT[20 + n][co0] = pack4bf(r1v);

            // global store: own col (final value)
#pragma unroll
            for (int i = 0; i < 4; ++i)
                buf[orow + (long long)(co0 + i) * chanStride +
                    (long long)ownc * colStride] = prevR[i];

            __syncthreads();
        }
    }
}

// out[b,c,s,r] = in[b,c,r,s] for each of the B*C planes.
__global__ __launch_bounds__(256) void transpose_kernel(
    const float* __restrict__ in, float* __restrict__ out,
    const int R, const int S)
{
    __shared__ float tile[32][33];
    const size_t plane = (size_t)blockIdx.z * R * S;
    const int s0 = blockIdx.x * 32;
    const int r0 = blockIdx.y * 32;
    const int tx = threadIdx.x;
    const int ty = threadIdx.y;
#pragma unroll
    for (int j = 0; j < 32; j += 8)
        tile[ty + j][tx] = in[plane + (size_t)(r0 + ty + j) * S + s0 + tx];
    __syncthreads();
#pragma unroll
    for (int j = 0; j < 32; j += 8)
        out[plane + (size_t)(s0 + ty + j) * R + r0 + tx] = tile[tx][ty + j];
}

static void launch_dir(float* buf, const float* w, const float* bias, int N,
                       long long rowStride, long long colStride,
                       long long chanStride, int startRow, int rowDir,
                       int numSteps, u64* halo, u64* tags, unsigned* xccmap,
                       u64 tagBase, bool persistent, hipStream_t stream)
{
    const int nblocks = 8 * (N / T_);   // 256 (N=512) or 128 (N=256)
    if (persistent) {
        scan_trap_kernel<<<nblocks, 256, 0, stream>>>(
            buf, w, bias, N, rowStride, colStride, chanStride, startRow,
            rowDir, numSteps, halo, tags, xccmap, tagBase);
    } else {
        for (int s = 0; s < numSteps; ++s)
            scan_trap_kernel<<<nblocks, 256, 0, stream>>>(
                buf, w, bias, N, rowStride, colStride, chanStride,
                startRow + s * rowDir, rowDir, 1, nullptr, nullptr, nullptr,
                0ull);
    }
}

extern "C" void kernel_launch(void* const* d_in, const int* in_sizes, int n_in,
                              void* d_out, int out_size, void* d_ws,
                              size_t ws_size, hipStream_t stream)
{
    const float* x    = (const float*)d_in[0];
    const float* w_ud = (const float*)d_in[1];
    const float* b_ud = (const float*)d_in[2];
    const float* w_du = (const float*)d_in[3];
    const float* b_du = (const float*)d_in[4];
    const float* w_lr = (const float*)d_in[5];
    const float* b_lr = (const float*)d_in[6];
    const float* w_rl = (const float*)d_in[7];
    const float* b_rl = (const float*)d_in[8];
    float* out = (float*)d_out;

    const size_t total = (size_t)B_ * C_ * H_ * W_;
    const long long chan = (long long)H_ * W_;

    const bool haveSync = ws_size >= TBUF_OFF;
    const bool haveT = ws_size >= TBUF_OFF + total * sizeof(float);

    u64* halo = (u64*)((char*)d_ws + HALO_OFF);
    u64* tags = (u64*)((char*)d_ws + TAG_OFF);
    float* wsT = (float*)((char*)d_ws + TBUF_OFF);

    hipMemcpyAsync(out, x, total * sizeof(float), hipMemcpyDeviceToDevice,
                   stream);
    if (haveSync) hipMemsetAsync(d_ws, 0, INIT_BYTES, stream);

    unsigned* xm[4];
    for (int d = 0; d < 4; ++d)
        xm[d] = (unsigned*)((char*)d_ws + XCC_OFF + d * 1024);

    // up->down / down->up on [b,c,h,w]: scan h, conv along w (contig, N=512)
    launch_dir(out, w_ud, b_ud, W_, (long long)W_, 1LL, chan,
               1, +1, H_ - 1, halo, tags, xm[0], 0ull << 20, haveSync,
               stream);
    launch_dir(out, w_du, b_du, W_, (long long)W_, 1LL, chan,
               H_ - 2, -1, H_ - 1, halo, tags, xm[1], 1ull << 20, haveSync,
               stream);

    if (haveT) {
        // transpose to [b,c,w,h]: scan w, conv along h (contig, N=256)
        {
            dim3 gt(W_ / 32, H_ / 32, B_ * C_);
            transpose_kernel<<<gt, dim3(32, 8), 0, stream>>>(out, wsT, H_, W_);
        }
        launch_dir(wsT, w_lr, b_lr, H_, (long long)H_, 1LL, chan,
                   1, +1, W_ - 1, halo, tags, xm[2], 2ull << 20, haveSync,
                   stream);
        launch_dir(wsT, w_rl, b_rl, H_, (long long)H_, 1LL, chan,
                   W_ - 2, -1, W_ - 1, halo, tags, xm[3], 3ull << 20,
                   haveSync, stream);
        {
            dim3 gt(H_ / 32, W_ / 32, B_ * C_);
            transpose_kernel<<<gt, dim3(32, 8), 0, stream>>>(wsT, out, W_, H_);
        }
    } else {
        // strided fallback on [b,c,h,w]: scan w (rowStride=1), conv along h
        launch_dir(out, w_lr, b_lr, H_, 1LL, (long long)W_, chan,
                   1, +1, W_ - 1, halo, tags, xm[2], 2ull << 20, haveSync,
                   stream);
        launch_dir(out, w_rl, b_rl, H_, 1LL, (long long)W_, chan,
                   W_ - 2, -1, W_ - 1, halo, tags, xm[3], 3ull << 20,
                   haveSync, stream);
    }
}